// Round 12
// baseline (45.122 us; speedup 1.0000x reference)
//
#include <hip/hip_runtime.h>
#include <math.h>

constexpr int IN_C = 31;
constexpr int TOT  = 44;
constexpr int HW   = 256 * 256;
constexpr int NPIX = 4 * HW;
constexpr float SMIN = 0.001f, SMAX = 1000.0f;

typedef __attribute__((ext_vector_type(8))) short bf16x8;
typedef __attribute__((ext_vector_type(4))) float f32x4;

__device__ __forceinline__ float frcp(float v) { return __builtin_amdgcn_rcpf(v); }

__device__ __forceinline__ short f2bf(float f) {
    union { float f; unsigned u; } v; v.f = f;
    unsigned r = v.u + 0x7FFFu + ((v.u >> 16) & 1u);   // RNE
    return (short)(r >> 16);
}
__device__ __forceinline__ float bf2f(short h) {
    union { unsigned u; float f; } v; v.u = ((unsigned)(unsigned short)h) << 16;
    return v.f;
}

// One thread per pixel, 256 threads/block = 4 waves, wave owns 64 pixels.
// Encoder GEMV as wave-level MFMA (12 tiles 16x16x32 bf16, 3-product split).
// Unified 8KB/wave LDS buffer (float2-XOR-swizzled [64][32] transpose, then
// reused for the two-phase S flush) -> 32KB/block -> 5 blocks/CU at VGPR<=102.
// S computed ROW-AT-A-TIME (stage+free) to keep register peak ~90.
__global__ __launch_bounds__(256, 5) void sepgpd_fused(
    const float* __restrict__ x,
    const float* __restrict__ Wenc,
    const float* __restrict__ benc,
    float* __restrict__ out)
{
    __shared__ float tbuf[4][2048];   // 32 KB: 4 waves x 8 KB unified

    const int tid  = threadIdx.x;
    const int lane = tid & 63;
    const int wid  = tid >> 6;
    const int W0   = blockIdx.x * 256 + wid * 64;   // wave's first pixel
    const int b    = W0 >> 16;                      // 64 | 65536: same image
    const int hwb  = W0 & (HW - 1);
    const int lrow = lane & 15;                     // M/N lane index
    const int lgrp = lane >> 4;                     // K group

    const float* xb = x + (size_t)b * IN_C * HW + hwb;
    float* wt = &tbuf[wid][0];

    // ---- B fragments: W^T tiles (48 chans x 32 K), hi/lo bf16 split ----
    bf16x8 bhi[3], blo[3];
#pragma unroll
    for (int n = 0; n < 3; ++n) {
        const int o = n * 16 + lrow;
#pragma unroll
        for (int j = 0; j < 8; ++j) {
            const int k = lgrp * 8 + j;
            const float wv = (o < TOT && k < IN_C) ? Wenc[o * IN_C + k] : 0.0f;
            const short h = f2bf(wv);
            bhi[n][j] = h;
            blo[n][j] = f2bf(wv - bf2f(h));
        }
    }

    // ---- MFMA: 4 M-tiles x 3 N-tiles x 3 products ----
    f32x4 acc[4][3];
#pragma unroll
    for (int t = 0; t < 4; ++t)
#pragma unroll
        for (int n = 0; n < 3; ++n) acc[t][n] = (f32x4)0.0f;

#pragma unroll
    for (int t = 0; t < 4; ++t) {
        float xf[8];
#pragma unroll
        for (int j = 0; j < 8; ++j) {
            const int k = lgrp * 8 + j;
            xf[j] = (k < IN_C) ? xb[(size_t)k * HW + t * 16 + lrow] : 0.0f;
        }
        bf16x8 ahi, alo;
#pragma unroll
        for (int j = 0; j < 8; ++j) {
            const short h = f2bf(xf[j]);
            ahi[j] = h;
            alo[j] = f2bf(xf[j] - bf2f(h));
        }
#pragma unroll
        for (int n = 0; n < 3; ++n) {
            acc[t][n] = __builtin_amdgcn_mfma_f32_16x16x32_bf16(ahi, bhi[n], acc[t][n], 0, 0, 0);
            acc[t][n] = __builtin_amdgcn_mfma_f32_16x16x32_bf16(alo, bhi[n], acc[t][n], 0, 0, 0);
            acc[t][n] = __builtin_amdgcn_mfma_f32_16x16x32_bf16(ahi, blo[n], acc[t][n], 0, 0, 0);
        }
    }

    // ---- LDS transpose, float2-XOR swizzle in [64][32] (wave-synchronous) ---
    // store chan c of pixel p at: p*32 + (((c>>1) ^ (p&15))<<1) + (c&1)
    float a44[TOT];

    // phase A: chans 0..31 (n-tiles 0,1); write <=2-way, read min-aliased
#pragma unroll
    for (int t = 0; t < 4; ++t)
#pragma unroll
        for (int n = 0; n < 2; ++n)
#pragma unroll
            for (int r = 0; r < 4; ++r) {
                const int p  = t * 16 + lgrp * 4 + r;     // pixel
                const int cp = n * 8 + (lrow >> 1);       // chan pair
                wt[p * 32 + (((cp ^ (p & 15)) << 1) | (lrow & 1))] = acc[t][n][r];
            }
    {
        const float2* w2 = reinterpret_cast<const float2*>(wt + lane * 32);
#pragma unroll
        for (int q = 0; q < 16; ++q) {
            const float2 v = w2[q ^ (lane & 15)];
            a44[2 * q]     = v.x;
            a44[2 * q + 1] = v.y;
        }
    }
    // phase B: chans 32..43 (n-tile 2), stored at pair index lrow>>1
#pragma unroll
    for (int t = 0; t < 4; ++t)
#pragma unroll
        for (int r = 0; r < 4; ++r) {
            const int p  = t * 16 + lgrp * 4 + r;
            const int cp = lrow >> 1;
            wt[p * 32 + (((cp ^ (p & 15)) << 1) | (lrow & 1))] = acc[t][2][r];
        }
    {
        const float2* w2 = reinterpret_cast<const float2*>(wt + lane * 32);
#pragma unroll
        for (int q = 0; q < 6; ++q) {
            const float2 v = w2[q ^ (lane & 15)];
            a44[32 + 2 * q]     = v.x;
            a44[32 + 2 * q + 1] = v.y;
        }
    }

    // ---- bias (uniform, scalar-cached) ----
#pragma unroll
    for (int o = 0; o < TOT; ++o) a44[o] += benc[o];

    // ---- m: first 8 channels, per-pixel contiguous ----
    const int pix = W0 + lane;
    float4* mp = reinterpret_cast<float4*>(out + (size_t)pix * 8);
    mp[0] = make_float4(a44[0], a44[1], a44[2], a44[3]);
    mp[1] = make_float4(a44[4], a44[5], a44[6], a44[7]);

    // ---- sqrt scales (rcp-based sigmoid) ----
    float sq[8];
#pragma unroll
    for (int j = 0; j < 8; ++j) {
        const float sig = frcp(1.0f + __expf(-a44[8 + j]));
        const float s   = fmaf(SMAX - SMIN, sig, SMIN);
        sq[j] = __builtin_amdgcn_sqrtf(s);
    }

    // ---- R from Givens chain; hw sin/cos in revolutions: cos(pi*th)=v_cos(th/2)
    float R[8][8];
#pragma unroll
    for (int i = 0; i < 8; ++i)
#pragma unroll
        for (int k = 0; k < 8; ++k) R[i][k] = (i == k) ? 1.0f : 0.0f;

    int cc = 0;
#pragma unroll
    for (int i = 0; i < 7; ++i) {
#pragma unroll
        for (int j = i + 1; j < 8; ++j) {
            const float wv  = a44[16 + cc];
            // tanh(wv) = 1 - 2/(e^{2wv}+1); saturates correctly for large |wv|
            const float th  = fmaf(-2.0f, frcp(__expf(2.0f * wv) + 1.0f), 1.0f);
            const float rev = 0.5f * th;
            const float cs  = __builtin_amdgcn_cosf(rev);
            const float ss  = __builtin_amdgcn_sinf(rev);
#pragma unroll
            for (int r = 0; r < 8; ++r) {
                const float ri = R[r][i];
                const float rj = R[r][j];
                R[r][i] = fmaf(ri, cs, rj * ss);
                R[r][j] = fmaf(rj, cs, -(ri * ss));
            }
            ++cc;
        }
    }

    // scale row j by sqrt(s_j):  S = (sqrtD R)^T (sqrtD R)
#pragma unroll
    for (int j = 0; j < 8; ++j)
#pragma unroll
        for (int k = 0; k < 8; ++k) R[j][k] *= sq[j];

    // ---- S rows computed one at a time, staged, flushed per 4-row phase ----
    float4* wbuf4 = reinterpret_cast<float4*>(wt);
    float4* S4 = reinterpret_cast<float4*>(out + (size_t)NPIX * 8);
    const size_t pixbase4 = (size_t)W0 * 16;   // float4 units

#pragma unroll
    for (int p = 0; p < 2; ++p) {
#pragma unroll
        for (int r = 0; r < 4; ++r) {
            const int i = 4 * p + r;
            float row[8];
#pragma unroll
            for (int k = 0; k < 8; ++k) {
                float d = 0.0f;
#pragma unroll
                for (int j = 0; j < 8; ++j) d = fmaf(R[j][i], R[j][k], d);
                row[k] = d;
            }
            const int v0 = r * 2, v1 = v0 + 1;
            wbuf4[lane * 8 + (v0 ^ (lane & 7))] =
                make_float4(row[0], row[1], row[2], row[3]);
            wbuf4[lane * 8 + (v1 ^ (lane & 7))] =
                make_float4(row[4], row[5], row[6], row[7]);
        }
        // coalesced flush: 8 iters x 64 lanes x 16B = 8KB contiguous
#pragma unroll
        for (int k = 0; k < 8; ++k) {
            const int t  = k * 64 + lane;
            const int pl = t >> 3;           // local pixel 0..63
            const int v  = t & 7;            // float4 index within half
            S4[pixbase4 + (size_t)pl * 16 + p * 8 + v] =
                wbuf4[pl * 8 + (v ^ (pl & 7))];
        }
    }
}

extern "C" void kernel_launch(void* const* d_in, const int* in_sizes, int n_in,
                              void* d_out, int out_size, void* d_ws, size_t ws_size,
                              hipStream_t stream)
{
    const float* x    = (const float*)d_in[0];
    const float* Wenc = (const float*)d_in[1];
    const float* benc = (const float*)d_in[2];
    float* out        = (float*)d_out;

    dim3 grid(NPIX / 256), block(256);
    sepgpd_fused<<<grid, block, 0, stream>>>(x, Wenc, benc, out);
}

// Round 13
// 35.077 us; speedup vs baseline: 1.2864x; 1.2864x over previous
//
#include <hip/hip_runtime.h>
#include <math.h>

constexpr int IN_C = 31;
constexpr int TOT  = 44;
constexpr int HW   = 256 * 256;
constexpr int NPIX = 4 * HW;
constexpr float SMIN = 0.001f, SMAX = 1000.0f;
constexpr float PI_F = 3.14159265358979323846f;

typedef __attribute__((ext_vector_type(8))) short bf16x8;
typedef __attribute__((ext_vector_type(4))) float f32x4;

__device__ __forceinline__ float frcp(float v) { return __builtin_amdgcn_rcpf(v); }

__device__ __forceinline__ short f2bf(float f) {
    union { float f; unsigned u; } v; v.f = f;
    unsigned r = v.u + 0x7FFFu + ((v.u >> 16) & 1u);   // RNE
    return (short)(r >> 16);
}
__device__ __forceinline__ float bf2f(short h) {
    union { unsigned u; float f; } v; v.u = ((unsigned)(unsigned short)h) << 16;
    return v.f;
}

// R11 structure (proven 34.6us) + ONE change: all 32 x-loads hoisted to the
// top of the kernel so their HBM latency hides under B-fragment building,
// instead of being exposed per M-tile inside the MFMA loop.
__global__ __launch_bounds__(256, 4) void sepgpd_fused(
    const float* __restrict__ x,
    const float* __restrict__ Wenc,
    const float* __restrict__ benc,
    float* __restrict__ out)
{
    __shared__ float tbuf[4][64 * 34];   // 4 waves x 8704 B (transpose + staging)

    const int tid  = threadIdx.x;
    const int lane = tid & 63;
    const int wid  = tid >> 6;
    const int W0   = blockIdx.x * 256 + wid * 64;   // wave's first pixel
    const int b    = W0 >> 16;                      // 64 | 65536: same image
    const int hwb  = W0 & (HW - 1);
    const int lrow = lane & 15;                     // M/N lane index
    const int lgrp = lane >> 4;                     // K group

    const float* xb = x + (size_t)b * IN_C * HW + hwb;
    float* wt = &tbuf[wid][0];

    // ---- x loads hoisted: 32 coalesced loads issued first, all in flight ----
    float xf[4][8];
#pragma unroll
    for (int t = 0; t < 4; ++t)
#pragma unroll
        for (int j = 0; j < 8; ++j) {
            const int k = lgrp * 8 + j;
            xf[t][j] = (k < IN_C) ? xb[(size_t)k * HW + t * 16 + lrow] : 0.0f;
        }

    // ---- B fragments: W^T tiles (48 chans x 32 K), hi/lo bf16 split ----
    // (L1-resident gathers + conversions — x loads return underneath this)
    bf16x8 bhi[3], blo[3];
#pragma unroll
    for (int n = 0; n < 3; ++n) {
        const int o = n * 16 + lrow;
#pragma unroll
        for (int j = 0; j < 8; ++j) {
            const int k = lgrp * 8 + j;
            const float wv = (o < TOT && k < IN_C) ? Wenc[o * IN_C + k] : 0.0f;
            const short h = f2bf(wv);
            bhi[n][j] = h;
            blo[n][j] = f2bf(wv - bf2f(h));
        }
    }

    // ---- MFMA: 4 M-tiles x 3 N-tiles x 3 products ----
    f32x4 acc[4][3];
#pragma unroll
    for (int t = 0; t < 4; ++t)
#pragma unroll
        for (int n = 0; n < 3; ++n) acc[t][n] = (f32x4)0.0f;

#pragma unroll
    for (int t = 0; t < 4; ++t) {
        bf16x8 ahi, alo;
#pragma unroll
        for (int j = 0; j < 8; ++j) {
            const short h = f2bf(xf[t][j]);
            ahi[j] = h;
            alo[j] = f2bf(xf[t][j] - bf2f(h));
        }
#pragma unroll
        for (int n = 0; n < 3; ++n) {
            acc[t][n] = __builtin_amdgcn_mfma_f32_16x16x32_bf16(ahi, bhi[n], acc[t][n], 0, 0, 0);
            acc[t][n] = __builtin_amdgcn_mfma_f32_16x16x32_bf16(alo, bhi[n], acc[t][n], 0, 0, 0);
            acc[t][n] = __builtin_amdgcn_mfma_f32_16x16x32_bf16(ahi, blo[n], acc[t][n], 0, 0, 0);
        }
    }

    // ---- two-phase LDS transpose -> per-lane a44 (wave-synchronous) ----
    float a44[TOT];

    // phase A: chans 0..31 (n-tiles 0,1)
#pragma unroll
    for (int t = 0; t < 4; ++t)
#pragma unroll
        for (int n = 0; n < 2; ++n)
#pragma unroll
            for (int r = 0; r < 4; ++r) {
                const int p = t * 16 + lgrp * 4 + r;      // pixel (C row)
                wt[p * 34 + n * 16 + lrow] = acc[t][n][r];
            }
    {
        const float2* w2 = reinterpret_cast<const float2*>(wt + lane * 34);
#pragma unroll
        for (int q = 0; q < 16; ++q) {
            const float2 v = w2[q];
            a44[2 * q]     = v.x;
            a44[2 * q + 1] = v.y;
        }
    }
    // phase B: chans 32..43 (n-tile 2; cols reused)
#pragma unroll
    for (int t = 0; t < 4; ++t)
#pragma unroll
        for (int r = 0; r < 4; ++r) {
            const int p = t * 16 + lgrp * 4 + r;
            wt[p * 34 + lrow] = acc[t][2][r];
        }
    {
        const float2* w2 = reinterpret_cast<const float2*>(wt + lane * 34);
#pragma unroll
        for (int q = 0; q < 6; ++q) {
            const float2 v = w2[q];
            a44[32 + 2 * q]     = v.x;
            a44[32 + 2 * q + 1] = v.y;
        }
    }

    // ---- bias (uniform, scalar-cached) ----
#pragma unroll
    for (int o = 0; o < TOT; ++o) a44[o] += benc[o];

    // ---- m: first 8 channels, per-pixel contiguous ----
    const int pix = W0 + lane;
    float4* mp = reinterpret_cast<float4*>(out + (size_t)pix * 8);
    mp[0] = make_float4(a44[0], a44[1], a44[2], a44[3]);
    mp[1] = make_float4(a44[4], a44[5], a44[6], a44[7]);

    // ---- sqrt scales (rcp-based sigmoid) ----
    float sq[8];
#pragma unroll
    for (int j = 0; j < 8; ++j) {
        const float sig = frcp(1.0f + __expf(-a44[8 + j]));
        const float s   = fmaf(SMAX - SMIN, sig, SMIN);
        sq[j] = __builtin_amdgcn_sqrtf(s);
    }

    // ---- R from Givens chain (identity const-folded by full unroll) ----
    float R[8][8];
#pragma unroll
    for (int i = 0; i < 8; ++i)
#pragma unroll
        for (int k = 0; k < 8; ++k) R[i][k] = (i == k) ? 1.0f : 0.0f;

    int cc = 0;
#pragma unroll
    for (int i = 0; i < 7; ++i) {
#pragma unroll
        for (int j = i + 1; j < 8; ++j) {
            const float wv = a44[16 + cc];
            // tanh(wv) = 1 - 2/(e^{2wv}+1); saturates correctly for large |wv|
            const float th = fmaf(-2.0f, frcp(__expf(2.0f * wv) + 1.0f), 1.0f);
            const float a  = PI_F * th;
            const float cs = __cosf(a);
            const float ss = __sinf(a);
#pragma unroll
            for (int r = 0; r < 8; ++r) {
                const float ri = R[r][i];
                const float rj = R[r][j];
                R[r][i] = fmaf(ri, cs, rj * ss);
                R[r][j] = fmaf(rj, cs, -(ri * ss));
            }
            ++cc;
        }
    }

    // scale row j by sqrt(s_j):  S = (sqrtD R)^T (sqrtD R)
#pragma unroll
    for (int j = 0; j < 8; ++j)
#pragma unroll
        for (int k = 0; k < 8; ++k) R[j][k] *= sq[j];

    float S[8][8];
#pragma unroll
    for (int i = 0; i < 8; ++i)
#pragma unroll
        for (int k = i; k < 8; ++k) {
            float d = 0.0f;
#pragma unroll
            for (int j = 0; j < 8; ++j) d = fmaf(R[j][i], R[j][k], d);
            S[i][k] = d; S[k][i] = d;
        }

    // ---- two-phase staged flush of S (reuses wt; wave-synchronous) ----
    float4* wbuf4 = reinterpret_cast<float4*>(wt);
    float4* S4 = reinterpret_cast<float4*>(out + (size_t)NPIX * 8);
    const size_t pixbase4 = (size_t)W0 * 16;   // float4 units

#pragma unroll
    for (int p = 0; p < 2; ++p) {
#pragma unroll
        for (int r = 0; r < 4; ++r) {
            const int i  = 4 * p + r;
            const int v0 = r * 2;
            const int v1 = v0 + 1;
            wbuf4[lane * 8 + (v0 ^ (lane & 7))] =
                make_float4(S[i][0], S[i][1], S[i][2], S[i][3]);
            wbuf4[lane * 8 + (v1 ^ (lane & 7))] =
                make_float4(S[i][4], S[i][5], S[i][6], S[i][7]);
        }
#pragma unroll
        for (int k = 0; k < 8; ++k) {
            const int t  = k * 64 + lane;
            const int pl = t >> 3;           // local pixel 0..63
            const int v  = t & 7;            // float4 index within half
            S4[pixbase4 + (size_t)pl * 16 + p * 8 + v] =
                wbuf4[pl * 8 + (v ^ (pl & 7))];
        }
    }
}

extern "C" void kernel_launch(void* const* d_in, const int* in_sizes, int n_in,
                              void* d_out, int out_size, void* d_ws, size_t ws_size,
                              hipStream_t stream)
{
    const float* x    = (const float*)d_in[0];
    const float* Wenc = (const float*)d_in[1];
    const float* benc = (const float*)d_in[2];
    float* out        = (float*)d_out;

    dim3 grid(NPIX / 256), block(256);
    sepgpd_fused<<<grid, block, 0, stream>>>(x, Wenc, benc, out);
}

// Round 17
// 34.734 us; speedup vs baseline: 1.2991x; 1.0099x over previous
//
#include <hip/hip_runtime.h>
#include <math.h>

constexpr int IN_C = 31;
constexpr int TOT  = 44;
constexpr int HW   = 256 * 256;
constexpr int NPIX = 4 * HW;
constexpr float SMIN = 0.001f, SMAX = 1000.0f;
constexpr float PI_F = 3.14159265358979323846f;

typedef __attribute__((ext_vector_type(8))) short bf16x8;
typedef __attribute__((ext_vector_type(4))) float f32x4;

__device__ __forceinline__ float frcp(float v) { return __builtin_amdgcn_rcpf(v); }

__device__ __forceinline__ short f2bf(float f) {
    union { float f; unsigned u; } v; v.f = f;
    unsigned r = v.u + 0x7FFFu + ((v.u >> 16) & 1u);   // RNE
    return (short)(r >> 16);
}
__device__ __forceinline__ float bf2f(short h) {
    union { unsigned u; float f; } v; v.u = ((unsigned)(unsigned short)h) << 16;
    return v.f;
}

// R11 (proven 34.6us, absmax 4.0) + ONE change: the per-M-tile x loads are
// software-pipelined one tile ahead (issue tile t+1's 8 loads before cvt+MFMA
// of tile t). Extra liveness = 8 floats -> no spill risk (R13's full-hoist
// spilled 32). DMA path abandoned (R14-R16: broken, condemned).
__global__ __launch_bounds__(256, 4) void sepgpd_fused(
    const float* __restrict__ x,
    const float* __restrict__ Wenc,
    const float* __restrict__ benc,
    float* __restrict__ out)
{
    __shared__ float tbuf[4][64 * 34];   // 4 waves x 8704 B (transpose + staging)

    const int tid  = threadIdx.x;
    const int lane = tid & 63;
    const int wid  = tid >> 6;
    const int W0   = blockIdx.x * 256 + wid * 64;   // wave's first pixel
    const int b    = W0 >> 16;                      // 64 | 65536: same image
    const int hwb  = W0 & (HW - 1);
    const int lrow = lane & 15;                     // M/N lane index
    const int lgrp = lane >> 4;                     // K group

    const float* xb = x + (size_t)b * IN_C * HW + hwb;
    float* wt = &tbuf[wid][0];

    // ---- B fragments: W^T tiles (48 chans x 32 K), hi/lo bf16 split ----
    bf16x8 bhi[3], blo[3];
#pragma unroll
    for (int n = 0; n < 3; ++n) {
        const int o = n * 16 + lrow;
#pragma unroll
        for (int j = 0; j < 8; ++j) {
            const int k = lgrp * 8 + j;
            const float wv = (o < TOT && k < IN_C) ? Wenc[o * IN_C + k] : 0.0f;
            const short h = f2bf(wv);
            bhi[n][j] = h;
            blo[n][j] = f2bf(wv - bf2f(h));
        }
    }

    // ---- MFMA: 4 M-tiles x 3 N-tiles x 3 products, x loads pipelined ----
    f32x4 acc[4][3];
#pragma unroll
    for (int t = 0; t < 4; ++t)
#pragma unroll
        for (int n = 0; n < 3; ++n) acc[t][n] = (f32x4)0.0f;

    float xcur[8], xnxt[8];
#pragma unroll
    for (int j = 0; j < 8; ++j) {
        const int k = lgrp * 8 + j;
        xcur[j] = (k < IN_C) ? xb[(size_t)k * HW + lrow] : 0.0f;   // tile 0
    }

#pragma unroll
    for (int t = 0; t < 4; ++t) {
        if (t < 3) {
#pragma unroll
            for (int j = 0; j < 8; ++j) {
                const int k = lgrp * 8 + j;
                xnxt[j] = (k < IN_C) ? xb[(size_t)k * HW + (t + 1) * 16 + lrow]
                                     : 0.0f;
            }
        }
        bf16x8 ahi, alo;
#pragma unroll
        for (int j = 0; j < 8; ++j) {
            const short h = f2bf(xcur[j]);
            ahi[j] = h;
            alo[j] = f2bf(xcur[j] - bf2f(h));
        }
#pragma unroll
        for (int n = 0; n < 3; ++n) {
            acc[t][n] = __builtin_amdgcn_mfma_f32_16x16x32_bf16(ahi, bhi[n], acc[t][n], 0, 0, 0);
            acc[t][n] = __builtin_amdgcn_mfma_f32_16x16x32_bf16(alo, bhi[n], acc[t][n], 0, 0, 0);
            acc[t][n] = __builtin_amdgcn_mfma_f32_16x16x32_bf16(ahi, blo[n], acc[t][n], 0, 0, 0);
        }
        if (t < 3) {
#pragma unroll
            for (int j = 0; j < 8; ++j) xcur[j] = xnxt[j];
        }
    }

    // ---- two-phase LDS transpose -> per-lane a44 (wave-synchronous) ----
    float a44[TOT];

    // phase A: chans 0..31 (n-tiles 0,1)
#pragma unroll
    for (int t = 0; t < 4; ++t)
#pragma unroll
        for (int n = 0; n < 2; ++n)
#pragma unroll
            for (int r = 0; r < 4; ++r) {
                const int p = t * 16 + lgrp * 4 + r;      // pixel (C row)
                wt[p * 34 + n * 16 + lrow] = acc[t][n][r];
            }
    {
        const float2* w2 = reinterpret_cast<const float2*>(wt + lane * 34);
#pragma unroll
        for (int q = 0; q < 16; ++q) {
            const float2 v = w2[q];
            a44[2 * q]     = v.x;
            a44[2 * q + 1] = v.y;
        }
    }
    // phase B: chans 32..43 (n-tile 2; cols reused)
#pragma unroll
    for (int t = 0; t < 4; ++t)
#pragma unroll
        for (int r = 0; r < 4; ++r) {
            const int p = t * 16 + lgrp * 4 + r;
            wt[p * 34 + lrow] = acc[t][2][r];
        }
    {
        const float2* w2 = reinterpret_cast<const float2*>(wt + lane * 34);
#pragma unroll
        for (int q = 0; q < 6; ++q) {
            const float2 v = w2[q];
            a44[32 + 2 * q]     = v.x;
            a44[32 + 2 * q + 1] = v.y;
        }
    }

    // ---- bias (uniform, scalar-cached) ----
#pragma unroll
    for (int o = 0; o < TOT; ++o) a44[o] += benc[o];

    // ---- m: first 8 channels, per-pixel contiguous ----
    const int pix = W0 + lane;
    float4* mp = reinterpret_cast<float4*>(out + (size_t)pix * 8);
    mp[0] = make_float4(a44[0], a44[1], a44[2], a44[3]);
    mp[1] = make_float4(a44[4], a44[5], a44[6], a44[7]);

    // ---- sqrt scales (rcp-based sigmoid) ----
    float sq[8];
#pragma unroll
    for (int j = 0; j < 8; ++j) {
        const float sig = frcp(1.0f + __expf(-a44[8 + j]));
        const float s   = fmaf(SMAX - SMIN, sig, SMIN);
        sq[j] = __builtin_amdgcn_sqrtf(s);
    }

    // ---- R from Givens chain (identity const-folded by full unroll) ----
    float R[8][8];
#pragma unroll
    for (int i = 0; i < 8; ++i)
#pragma unroll
        for (int k = 0; k < 8; ++k) R[i][k] = (i == k) ? 1.0f : 0.0f;

    int cc = 0;
#pragma unroll
    for (int i = 0; i < 7; ++i) {
#pragma unroll
        for (int j = i + 1; j < 8; ++j) {
            const float wv = a44[16 + cc];
            // tanh(wv) = 1 - 2/(e^{2wv}+1); saturates correctly for large |wv|
            const float th = fmaf(-2.0f, frcp(__expf(2.0f * wv) + 1.0f), 1.0f);
            const float a  = PI_F * th;
            const float cs = __cosf(a);
            const float ss = __sinf(a);
#pragma unroll
            for (int r = 0; r < 8; ++r) {
                const float ri = R[r][i];
                const float rj = R[r][j];
                R[r][i] = fmaf(ri, cs, rj * ss);
                R[r][j] = fmaf(rj, cs, -(ri * ss));
            }
            ++cc;
        }
    }

    // scale row j by sqrt(s_j):  S = (sqrtD R)^T (sqrtD R)
#pragma unroll
    for (int j = 0; j < 8; ++j)
#pragma unroll
        for (int k = 0; k < 8; ++k) R[j][k] *= sq[j];

    float S[8][8];
#pragma unroll
    for (int i = 0; i < 8; ++i)
#pragma unroll
        for (int k = i; k < 8; ++k) {
            float d = 0.0f;
#pragma unroll
            for (int j = 0; j < 8; ++j) d = fmaf(R[j][i], R[j][k], d);
            S[i][k] = d; S[k][i] = d;
        }

    // ---- two-phase staged flush of S (reuses wt; wave-synchronous) ----
    float4* wbuf4 = reinterpret_cast<float4*>(wt);
    float4* S4 = reinterpret_cast<float4*>(out + (size_t)NPIX * 8);
    const size_t pixbase4 = (size_t)W0 * 16;   // float4 units

#pragma unroll
    for (int p = 0; p < 2; ++p) {
#pragma unroll
        for (int r = 0; r < 4; ++r) {
            const int i  = 4 * p + r;
            const int v0 = r * 2;
            const int v1 = v0 + 1;
            wbuf4[lane * 8 + (v0 ^ (lane & 7))] =
                make_float4(S[i][0], S[i][1], S[i][2], S[i][3]);
            wbuf4[lane * 8 + (v1 ^ (lane & 7))] =
                make_float4(S[i][4], S[i][5], S[i][6], S[i][7]);
        }
#pragma unroll
        for (int k = 0; k < 8; ++k) {
            const int t  = k * 64 + lane;
            const int pl = t >> 3;           // local pixel 0..63
            const int v  = t & 7;            // float4 index within half
            S4[pixbase4 + (size_t)pl * 16 + p * 8 + v] =
                wbuf4[pl * 8 + (v ^ (pl & 7))];
        }
    }
}

extern "C" void kernel_launch(void* const* d_in, const int* in_sizes, int n_in,
                              void* d_out, int out_size, void* d_ws, size_t ws_size,
                              hipStream_t stream)
{
    const float* x    = (const float*)d_in[0];
    const float* Wenc = (const float*)d_in[1];
    const float* benc = (const float*)d_in[2];
    float* out        = (float*)d_out;

    dim3 grid(NPIX / 256), block(256);
    sepgpd_fused<<<grid, block, 0, stream>>>(x, Wenc, benc, out);
}

// Round 18
// 34.705 us; speedup vs baseline: 1.3001x; 1.0008x over previous
//
#include <hip/hip_runtime.h>
#include <math.h>

constexpr int IN_C = 31;
constexpr int TOT  = 44;
constexpr int HW   = 256 * 256;
constexpr int NPIX = 4 * HW;
constexpr float SMIN = 0.001f, SMAX = 1000.0f;

typedef __attribute__((ext_vector_type(8))) short bf16x8;
typedef __attribute__((ext_vector_type(4))) float f32x4;

__device__ __forceinline__ float frcp(float v) { return __builtin_amdgcn_rcpf(v); }

__device__ __forceinline__ short f2bf(float f) {
    union { float f; unsigned u; } v; v.f = f;
    unsigned r = v.u + 0x7FFFu + ((v.u >> 16) & 1u);   // RNE
    return (short)(r >> 16);
}
__device__ __forceinline__ float bf2f(short h) {
    union { unsigned u; float f; } v; v.u = ((unsigned)(unsigned short)h) << 16;
    return v.f;
}

// R17 base (proven 34.7us, absmax 4.0) + two register-neutral changes:
//  1) Wenc staged once per block into LDS via 6 coalesced loads; B fragments
//     built from LDS (2-way banks = free) instead of 24 per-lane global
//     gathers/wave (~60 cache lines each, TA-serialized across 16 waves/CU).
//  2) Givens sin/cos in hardware revolutions (R12-validated numerics):
//     cos(pi*th) = v_cos(th/2) — drops libm range-reduction VALU work.
__global__ __launch_bounds__(256, 4) void sepgpd_fused(
    const float* __restrict__ x,
    const float* __restrict__ Wenc,
    const float* __restrict__ benc,
    float* __restrict__ out)
{
    __shared__ float tbuf[4][64 * 34];   // 4 waves x 8704 B (transpose + staging)
    __shared__ float wsh[TOT * IN_C + 4]; // 5.5 KB staged weights (block-shared)

    const int tid  = threadIdx.x;
    const int lane = tid & 63;
    const int wid  = tid >> 6;
    const int W0   = blockIdx.x * 256 + wid * 64;   // wave's first pixel
    const int b    = W0 >> 16;                      // 64 | 65536: same image
    const int hwb  = W0 & (HW - 1);
    const int lrow = lane & 15;                     // M/N lane index
    const int lgrp = lane >> 4;                     // K group

    const float* xb = x + (size_t)b * IN_C * HW + hwb;
    float* wt = &tbuf[wid][0];

    // ---- cooperative coalesced weight staging (6 iters of 256 lanes) ----
    for (int idx = tid; idx < TOT * IN_C; idx += 256) wsh[idx] = Wenc[idx];
    __syncthreads();

    // ---- B fragments from LDS (2-way bank = free), hi/lo bf16 split ----
    bf16x8 bhi[3], blo[3];
#pragma unroll
    for (int n = 0; n < 3; ++n) {
        const int o = n * 16 + lrow;
#pragma unroll
        for (int j = 0; j < 8; ++j) {
            const int k = lgrp * 8 + j;
            const float wv = (o < TOT && k < IN_C) ? wsh[o * IN_C + k] : 0.0f;
            const short h = f2bf(wv);
            bhi[n][j] = h;
            blo[n][j] = f2bf(wv - bf2f(h));
        }
    }

    // ---- MFMA: 4 M-tiles x 3 N-tiles x 3 products, x loads pipelined ----
    f32x4 acc[4][3];
#pragma unroll
    for (int t = 0; t < 4; ++t)
#pragma unroll
        for (int n = 0; n < 3; ++n) acc[t][n] = (f32x4)0.0f;

    float xcur[8], xnxt[8];
#pragma unroll
    for (int j = 0; j < 8; ++j) {
        const int k = lgrp * 8 + j;
        xcur[j] = (k < IN_C) ? xb[(size_t)k * HW + lrow] : 0.0f;   // tile 0
    }

#pragma unroll
    for (int t = 0; t < 4; ++t) {
        if (t < 3) {
#pragma unroll
            for (int j = 0; j < 8; ++j) {
                const int k = lgrp * 8 + j;
                xnxt[j] = (k < IN_C) ? xb[(size_t)k * HW + (t + 1) * 16 + lrow]
                                     : 0.0f;
            }
        }
        bf16x8 ahi, alo;
#pragma unroll
        for (int j = 0; j < 8; ++j) {
            const short h = f2bf(xcur[j]);
            ahi[j] = h;
            alo[j] = f2bf(xcur[j] - bf2f(h));
        }
#pragma unroll
        for (int n = 0; n < 3; ++n) {
            acc[t][n] = __builtin_amdgcn_mfma_f32_16x16x32_bf16(ahi, bhi[n], acc[t][n], 0, 0, 0);
            acc[t][n] = __builtin_amdgcn_mfma_f32_16x16x32_bf16(alo, bhi[n], acc[t][n], 0, 0, 0);
            acc[t][n] = __builtin_amdgcn_mfma_f32_16x16x32_bf16(ahi, blo[n], acc[t][n], 0, 0, 0);
        }
        if (t < 3) {
#pragma unroll
            for (int j = 0; j < 8; ++j) xcur[j] = xnxt[j];
        }
    }

    // ---- two-phase LDS transpose -> per-lane a44 (wave-synchronous) ----
    float a44[TOT];

    // phase A: chans 0..31 (n-tiles 0,1)
#pragma unroll
    for (int t = 0; t < 4; ++t)
#pragma unroll
        for (int n = 0; n < 2; ++n)
#pragma unroll
            for (int r = 0; r < 4; ++r) {
                const int p = t * 16 + lgrp * 4 + r;      // pixel (C row)
                wt[p * 34 + n * 16 + lrow] = acc[t][n][r];
            }
    {
        const float2* w2 = reinterpret_cast<const float2*>(wt + lane * 34);
#pragma unroll
        for (int q = 0; q < 16; ++q) {
            const float2 v = w2[q];
            a44[2 * q]     = v.x;
            a44[2 * q + 1] = v.y;
        }
    }
    // phase B: chans 32..43 (n-tile 2; cols reused)
#pragma unroll
    for (int t = 0; t < 4; ++t)
#pragma unroll
        for (int r = 0; r < 4; ++r) {
            const int p = t * 16 + lgrp * 4 + r;
            wt[p * 34 + lrow] = acc[t][2][r];
        }
    {
        const float2* w2 = reinterpret_cast<const float2*>(wt + lane * 34);
#pragma unroll
        for (int q = 0; q < 6; ++q) {
            const float2 v = w2[q];
            a44[32 + 2 * q]     = v.x;
            a44[32 + 2 * q + 1] = v.y;
        }
    }

    // ---- bias (uniform, scalar-cached) ----
#pragma unroll
    for (int o = 0; o < TOT; ++o) a44[o] += benc[o];

    // ---- m: first 8 channels, per-pixel contiguous ----
    const int pix = W0 + lane;
    float4* mp = reinterpret_cast<float4*>(out + (size_t)pix * 8);
    mp[0] = make_float4(a44[0], a44[1], a44[2], a44[3]);
    mp[1] = make_float4(a44[4], a44[5], a44[6], a44[7]);

    // ---- sqrt scales (rcp-based sigmoid) ----
    float sq[8];
#pragma unroll
    for (int j = 0; j < 8; ++j) {
        const float sig = frcp(1.0f + __expf(-a44[8 + j]));
        const float s   = fmaf(SMAX - SMIN, sig, SMIN);
        sq[j] = __builtin_amdgcn_sqrtf(s);
    }

    // ---- R from Givens chain; hw sin/cos in revolutions (R12-validated):
    //      cos(pi*th) = v_cos(th/2), sin(pi*th) = v_sin(th/2) ----
    float R[8][8];
#pragma unroll
    for (int i = 0; i < 8; ++i)
#pragma unroll
        for (int k = 0; k < 8; ++k) R[i][k] = (i == k) ? 1.0f : 0.0f;

    int cc = 0;
#pragma unroll
    for (int i = 0; i < 7; ++i) {
#pragma unroll
        for (int j = i + 1; j < 8; ++j) {
            const float wv  = a44[16 + cc];
            // tanh(wv) = 1 - 2/(e^{2wv}+1); saturates correctly for large |wv|
            const float th  = fmaf(-2.0f, frcp(__expf(2.0f * wv) + 1.0f), 1.0f);
            const float rev = 0.5f * th;
            const float cs  = __builtin_amdgcn_cosf(rev);
            const float ss  = __builtin_amdgcn_sinf(rev);
#pragma unroll
            for (int r = 0; r < 8; ++r) {
                const float ri = R[r][i];
                const float rj = R[r][j];
                R[r][i] = fmaf(ri, cs, rj * ss);
                R[r][j] = fmaf(rj, cs, -(ri * ss));
            }
            ++cc;
        }
    }

    // scale row j by sqrt(s_j):  S = (sqrtD R)^T (sqrtD R)
#pragma unroll
    for (int j = 0; j < 8; ++j)
#pragma unroll
        for (int k = 0; k < 8; ++k) R[j][k] *= sq[j];

    float S[8][8];
#pragma unroll
    for (int i = 0; i < 8; ++i)
#pragma unroll
        for (int k = i; k < 8; ++k) {
            float d = 0.0f;
#pragma unroll
            for (int j = 0; j < 8; ++j) d = fmaf(R[j][i], R[j][k], d);
            S[i][k] = d; S[k][i] = d;
        }

    // ---- two-phase staged flush of S (reuses wt; wave-synchronous) ----
    float4* wbuf4 = reinterpret_cast<float4*>(wt);
    float4* S4 = reinterpret_cast<float4*>(out + (size_t)NPIX * 8);
    const size_t pixbase4 = (size_t)W0 * 16;   // float4 units

#pragma unroll
    for (int p = 0; p < 2; ++p) {
#pragma unroll
        for (int r = 0; r < 4; ++r) {
            const int i  = 4 * p + r;
            const int v0 = r * 2;
            const int v1 = v0 + 1;
            wbuf4[lane * 8 + (v0 ^ (lane & 7))] =
                make_float4(S[i][0], S[i][1], S[i][2], S[i][3]);
            wbuf4[lane * 8 + (v1 ^ (lane & 7))] =
                make_float4(S[i][4], S[i][5], S[i][6], S[i][7]);
        }
#pragma unroll
        for (int k = 0; k < 8; ++k) {
            const int t  = k * 64 + lane;
            const int pl = t >> 3;           // local pixel 0..63
            const int v  = t & 7;            // float4 index within half
            S4[pixbase4 + (size_t)pl * 16 + p * 8 + v] =
                wbuf4[pl * 8 + (v ^ (pl & 7))];
        }
    }
}

extern "C" void kernel_launch(void* const* d_in, const int* in_sizes, int n_in,
                              void* d_out, int out_size, void* d_ws, size_t ws_size,
                              hipStream_t stream)
{
    const float* x    = (const float*)d_in[0];
    const float* Wenc = (const float*)d_in[1];
    const float* benc = (const float*)d_in[2];
    float* out        = (float*)d_out;

    dim3 grid(NPIX / 256), block(256);
    sepgpd_fused<<<grid, block, 0, stream>>>(x, Wenc, benc, out);
}

// Round 19
// 27.460 us; speedup vs baseline: 1.6432x; 1.2638x over previous
//
#include <hip/hip_runtime.h>
#include <math.h>

constexpr int IN_C = 31;
constexpr int TOT  = 44;
constexpr int HW   = 256 * 256;
constexpr int NPIX = 4 * HW;
constexpr float SMIN = 0.001f, SMAX = 1000.0f;

typedef __attribute__((ext_vector_type(8))) short bf16x8;
typedef __attribute__((ext_vector_type(4))) float f32x4;

__device__ __forceinline__ float frcp(float v) { return __builtin_amdgcn_rcpf(v); }

__device__ __forceinline__ short f2bf(float f) {
    union { float f; unsigned u; } v; v.f = f;
    unsigned r = v.u + 0x7FFFu + ((v.u >> 16) & 1u);   // RNE
    return (short)(r >> 16);
}
__device__ __forceinline__ float bf2f(short h) {
    union { unsigned u; float f; } v; v.u = ((unsigned)(unsigned short)h) << 16;
    return v.f;
}

// R18 compute structure reshaped to ONE WAVE PER BLOCK (64 thd, grid 4096):
// independent single-wave workgroups de-lockstep the per-SIMD wave cohort
// (waves at different phases fill each other's stalls; CP refills blocks as
// they finish). No barriers anywhere. LDS 8704 B/block.
__global__ __launch_bounds__(64, 4) void sepgpd_fused(
    const float* __restrict__ x,
    const float* __restrict__ Wenc,
    const float* __restrict__ benc,
    float* __restrict__ out)
{
    __shared__ float wt[64 * 34];   // 8704 B: transpose + S staging

    const int lane = threadIdx.x;                   // 0..63
    const int W0   = blockIdx.x * 64;               // wave's first pixel
    const int b    = W0 >> 16;                      // 64 | 65536: same image
    const int hwb  = W0 & (HW - 1);
    const int lrow = lane & 15;                     // M/N lane index
    const int lgrp = lane >> 4;                     // K group

    const float* xb = x + (size_t)b * IN_C * HW + hwb;

    // ---- B fragments: W^T tiles (48 chans x 32 K), hi/lo bf16 split ----
    bf16x8 bhi[3], blo[3];
#pragma unroll
    for (int n = 0; n < 3; ++n) {
        const int o = n * 16 + lrow;
#pragma unroll
        for (int j = 0; j < 8; ++j) {
            const int k = lgrp * 8 + j;
            const float wv = (o < TOT && k < IN_C) ? Wenc[o * IN_C + k] : 0.0f;
            const short h = f2bf(wv);
            bhi[n][j] = h;
            blo[n][j] = f2bf(wv - bf2f(h));
        }
    }

    // ---- MFMA: 4 M-tiles x 3 N-tiles x 3 products, x loads pipelined ----
    f32x4 acc[4][3];
#pragma unroll
    for (int t = 0; t < 4; ++t)
#pragma unroll
        for (int n = 0; n < 3; ++n) acc[t][n] = (f32x4)0.0f;

    float xcur[8], xnxt[8];
#pragma unroll
    for (int j = 0; j < 8; ++j) {
        const int k = lgrp * 8 + j;
        xcur[j] = (k < IN_C) ? xb[(size_t)k * HW + lrow] : 0.0f;   // tile 0
    }

#pragma unroll
    for (int t = 0; t < 4; ++t) {
        if (t < 3) {
#pragma unroll
            for (int j = 0; j < 8; ++j) {
                const int k = lgrp * 8 + j;
                xnxt[j] = (k < IN_C) ? xb[(size_t)k * HW + (t + 1) * 16 + lrow]
                                     : 0.0f;
            }
        }
        bf16x8 ahi, alo;
#pragma unroll
        for (int j = 0; j < 8; ++j) {
            const short h = f2bf(xcur[j]);
            ahi[j] = h;
            alo[j] = f2bf(xcur[j] - bf2f(h));
        }
#pragma unroll
        for (int n = 0; n < 3; ++n) {
            acc[t][n] = __builtin_amdgcn_mfma_f32_16x16x32_bf16(ahi, bhi[n], acc[t][n], 0, 0, 0);
            acc[t][n] = __builtin_amdgcn_mfma_f32_16x16x32_bf16(alo, bhi[n], acc[t][n], 0, 0, 0);
            acc[t][n] = __builtin_amdgcn_mfma_f32_16x16x32_bf16(ahi, blo[n], acc[t][n], 0, 0, 0);
        }
        if (t < 3) {
#pragma unroll
            for (int j = 0; j < 8; ++j) xcur[j] = xnxt[j];
        }
    }

    // ---- two-phase LDS transpose -> per-lane a44 (wave-synchronous) ----
    float a44[TOT];

    // phase A: chans 0..31 (n-tiles 0,1)
#pragma unroll
    for (int t = 0; t < 4; ++t)
#pragma unroll
        for (int n = 0; n < 2; ++n)
#pragma unroll
            for (int r = 0; r < 4; ++r) {
                const int p = t * 16 + lgrp * 4 + r;      // pixel (C row)
                wt[p * 34 + n * 16 + lrow] = acc[t][n][r];
            }
    {
        const float2* w2 = reinterpret_cast<const float2*>(wt + lane * 34);
#pragma unroll
        for (int q = 0; q < 16; ++q) {
            const float2 v = w2[q];
            a44[2 * q]     = v.x;
            a44[2 * q + 1] = v.y;
        }
    }
    // phase B: chans 32..43 (n-tile 2; cols reused)
#pragma unroll
    for (int t = 0; t < 4; ++t)
#pragma unroll
        for (int r = 0; r < 4; ++r) {
            const int p = t * 16 + lgrp * 4 + r;
            wt[p * 34 + lrow] = acc[t][2][r];
        }
    {
        const float2* w2 = reinterpret_cast<const float2*>(wt + lane * 34);
#pragma unroll
        for (int q = 0; q < 6; ++q) {
            const float2 v = w2[q];
            a44[32 + 2 * q]     = v.x;
            a44[32 + 2 * q + 1] = v.y;
        }
    }

    // ---- bias (uniform, scalar-cached) ----
#pragma unroll
    for (int o = 0; o < TOT; ++o) a44[o] += benc[o];

    // ---- m: first 8 channels, per-pixel contiguous ----
    const int pix = W0 + lane;
    float4* mp = reinterpret_cast<float4*>(out + (size_t)pix * 8);
    mp[0] = make_float4(a44[0], a44[1], a44[2], a44[3]);
    mp[1] = make_float4(a44[4], a44[5], a44[6], a44[7]);

    // ---- sqrt scales (rcp-based sigmoid) ----
    float sq[8];
#pragma unroll
    for (int j = 0; j < 8; ++j) {
        const float sig = frcp(1.0f + __expf(-a44[8 + j]));
        const float s   = fmaf(SMAX - SMIN, sig, SMIN);
        sq[j] = __builtin_amdgcn_sqrtf(s);
    }

    // ---- R from Givens chain; hw sin/cos in revolutions (R12-validated):
    //      cos(pi*th) = v_cos(th/2), sin(pi*th) = v_sin(th/2) ----
    float R[8][8];
#pragma unroll
    for (int i = 0; i < 8; ++i)
#pragma unroll
        for (int k = 0; k < 8; ++k) R[i][k] = (i == k) ? 1.0f : 0.0f;

    int cc = 0;
#pragma unroll
    for (int i = 0; i < 7; ++i) {
#pragma unroll
        for (int j = i + 1; j < 8; ++j) {
            const float wv  = a44[16 + cc];
            // tanh(wv) = 1 - 2/(e^{2wv}+1); saturates correctly for large |wv|
            const float th  = fmaf(-2.0f, frcp(__expf(2.0f * wv) + 1.0f), 1.0f);
            const float rev = 0.5f * th;
            const float cs  = __builtin_amdgcn_cosf(rev);
            const float ss  = __builtin_amdgcn_sinf(rev);
#pragma unroll
            for (int r = 0; r < 8; ++r) {
                const float ri = R[r][i];
                const float rj = R[r][j];
                R[r][i] = fmaf(ri, cs, rj * ss);
                R[r][j] = fmaf(rj, cs, -(ri * ss));
            }
            ++cc;
        }
    }

    // scale row j by sqrt(s_j):  S = (sqrtD R)^T (sqrtD R)
#pragma unroll
    for (int j = 0; j < 8; ++j)
#pragma unroll
        for (int k = 0; k < 8; ++k) R[j][k] *= sq[j];

    float S[8][8];
#pragma unroll
    for (int i = 0; i < 8; ++i)
#pragma unroll
        for (int k = i; k < 8; ++k) {
            float d = 0.0f;
#pragma unroll
            for (int j = 0; j < 8; ++j) d = fmaf(R[j][i], R[j][k], d);
            S[i][k] = d; S[k][i] = d;
        }

    // ---- two-phase staged flush of S (reuses wt; wave-synchronous) ----
    float4* wbuf4 = reinterpret_cast<float4*>(wt);
    float4* S4 = reinterpret_cast<float4*>(out + (size_t)NPIX * 8);
    const size_t pixbase4 = (size_t)W0 * 16;   // float4 units

#pragma unroll
    for (int p = 0; p < 2; ++p) {
#pragma unroll
        for (int r = 0; r < 4; ++r) {
            const int i  = 4 * p + r;
            const int v0 = r * 2;
            const int v1 = v0 + 1;
            wbuf4[lane * 8 + (v0 ^ (lane & 7))] =
                make_float4(S[i][0], S[i][1], S[i][2], S[i][3]);
            wbuf4[lane * 8 + (v1 ^ (lane & 7))] =
                make_float4(S[i][4], S[i][5], S[i][6], S[i][7]);
        }
#pragma unroll
        for (int k = 0; k < 8; ++k) {
            const int t  = k * 64 + lane;
            const int pl = t >> 3;           // local pixel 0..63
            const int v  = t & 7;            // float4 index within half
            S4[pixbase4 + (size_t)pl * 16 + p * 8 + v] =
                wbuf4[pl * 8 + (v ^ (pl & 7))];
        }
    }
}

extern "C" void kernel_launch(void* const* d_in, const int* in_sizes, int n_in,
                              void* d_out, int out_size, void* d_ws, size_t ws_size,
                              hipStream_t stream)
{
    const float* x    = (const float*)d_in[0];
    const float* Wenc = (const float*)d_in[1];
    const float* benc = (const float*)d_in[2];
    float* out        = (float*)d_out;

    dim3 grid(NPIX / 64), block(64);
    sepgpd_fused<<<grid, block, 0, stream>>>(x, Wenc, benc, out);
}

// Round 20
// 27.435 us; speedup vs baseline: 1.6447x; 1.0009x over previous
//
#include <hip/hip_runtime.h>
#include <math.h>

constexpr int IN_C = 31;
constexpr int TOT  = 44;
constexpr int HW   = 256 * 256;
constexpr int NPIX = 4 * HW;
constexpr float SMIN = 0.001f, SMAX = 1000.0f;

typedef __attribute__((ext_vector_type(8))) short bf16x8;
typedef __attribute__((ext_vector_type(4))) float f32x4;

__device__ __forceinline__ float frcp(float v) { return __builtin_amdgcn_rcpf(v); }

__device__ __forceinline__ short f2bf(float f) {
    union { float f; unsigned u; } v; v.f = f;
    unsigned r = v.u + 0x7FFFu + ((v.u >> 16) & 1u);   // RNE
    return (short)(r >> 16);
}
__device__ __forceinline__ float bf2f(short h) {
    union { unsigned u; float f; } v; v.u = ((unsigned)(unsigned short)h) << 16;
    return v.f;
}

// R19 (proven 27.5us: 1-wave blocks, de-lockstepped) + ONE change: S computed
// ROW-AT-A-TIME straight into the LDS staging (8 transient regs instead of a
// 64-reg S array) -> VGPR ~100 -> 5 waves/SIMD natural occupancy (+25% TLP).
// launch_bounds stays (64,4): upper cap only, no forced-bound spill risk.
__global__ __launch_bounds__(64, 4) void sepgpd_fused(
    const float* __restrict__ x,
    const float* __restrict__ Wenc,
    const float* __restrict__ benc,
    float* __restrict__ out)
{
    __shared__ float wt[64 * 34];   // 8704 B: transpose + S staging

    const int lane = threadIdx.x;                   // 0..63
    const int W0   = blockIdx.x * 64;               // wave's first pixel
    const int b    = W0 >> 16;                      // 64 | 65536: same image
    const int hwb  = W0 & (HW - 1);
    const int lrow = lane & 15;                     // M/N lane index
    const int lgrp = lane >> 4;                     // K group

    const float* xb = x + (size_t)b * IN_C * HW + hwb;

    // ---- B fragments: W^T tiles (48 chans x 32 K), hi/lo bf16 split ----
    bf16x8 bhi[3], blo[3];
#pragma unroll
    for (int n = 0; n < 3; ++n) {
        const int o = n * 16 + lrow;
#pragma unroll
        for (int j = 0; j < 8; ++j) {
            const int k = lgrp * 8 + j;
            const float wv = (o < TOT && k < IN_C) ? Wenc[o * IN_C + k] : 0.0f;
            const short h = f2bf(wv);
            bhi[n][j] = h;
            blo[n][j] = f2bf(wv - bf2f(h));
        }
    }

    // ---- MFMA: 4 M-tiles x 3 N-tiles x 3 products, x loads pipelined ----
    f32x4 acc[4][3];
#pragma unroll
    for (int t = 0; t < 4; ++t)
#pragma unroll
        for (int n = 0; n < 3; ++n) acc[t][n] = (f32x4)0.0f;

    float xcur[8], xnxt[8];
#pragma unroll
    for (int j = 0; j < 8; ++j) {
        const int k = lgrp * 8 + j;
        xcur[j] = (k < IN_C) ? xb[(size_t)k * HW + lrow] : 0.0f;   // tile 0
    }

#pragma unroll
    for (int t = 0; t < 4; ++t) {
        if (t < 3) {
#pragma unroll
            for (int j = 0; j < 8; ++j) {
                const int k = lgrp * 8 + j;
                xnxt[j] = (k < IN_C) ? xb[(size_t)k * HW + (t + 1) * 16 + lrow]
                                     : 0.0f;
            }
        }
        bf16x8 ahi, alo;
#pragma unroll
        for (int j = 0; j < 8; ++j) {
            const short h = f2bf(xcur[j]);
            ahi[j] = h;
            alo[j] = f2bf(xcur[j] - bf2f(h));
        }
#pragma unroll
        for (int n = 0; n < 3; ++n) {
            acc[t][n] = __builtin_amdgcn_mfma_f32_16x16x32_bf16(ahi, bhi[n], acc[t][n], 0, 0, 0);
            acc[t][n] = __builtin_amdgcn_mfma_f32_16x16x32_bf16(alo, bhi[n], acc[t][n], 0, 0, 0);
            acc[t][n] = __builtin_amdgcn_mfma_f32_16x16x32_bf16(ahi, blo[n], acc[t][n], 0, 0, 0);
        }
        if (t < 3) {
#pragma unroll
            for (int j = 0; j < 8; ++j) xcur[j] = xnxt[j];
        }
    }

    // ---- two-phase LDS transpose -> per-lane a44 (wave-synchronous) ----
    float a44[TOT];

    // phase A: chans 0..31 (n-tiles 0,1)
#pragma unroll
    for (int t = 0; t < 4; ++t)
#pragma unroll
        for (int n = 0; n < 2; ++n)
#pragma unroll
            for (int r = 0; r < 4; ++r) {
                const int p = t * 16 + lgrp * 4 + r;      // pixel (C row)
                wt[p * 34 + n * 16 + lrow] = acc[t][n][r];
            }
    {
        const float2* w2 = reinterpret_cast<const float2*>(wt + lane * 34);
#pragma unroll
        for (int q = 0; q < 16; ++q) {
            const float2 v = w2[q];
            a44[2 * q]     = v.x;
            a44[2 * q + 1] = v.y;
        }
    }
    // phase B: chans 32..43 (n-tile 2; cols reused)
#pragma unroll
    for (int t = 0; t < 4; ++t)
#pragma unroll
        for (int r = 0; r < 4; ++r) {
            const int p = t * 16 + lgrp * 4 + r;
            wt[p * 34 + lrow] = acc[t][2][r];
        }
    {
        const float2* w2 = reinterpret_cast<const float2*>(wt + lane * 34);
#pragma unroll
        for (int q = 0; q < 6; ++q) {
            const float2 v = w2[q];
            a44[32 + 2 * q]     = v.x;
            a44[32 + 2 * q + 1] = v.y;
        }
    }

    // ---- bias (uniform, scalar-cached) ----
#pragma unroll
    for (int o = 0; o < TOT; ++o) a44[o] += benc[o];

    // ---- m: first 8 channels, per-pixel contiguous ----
    const int pix = W0 + lane;
    float4* mp = reinterpret_cast<float4*>(out + (size_t)pix * 8);
    mp[0] = make_float4(a44[0], a44[1], a44[2], a44[3]);
    mp[1] = make_float4(a44[4], a44[5], a44[6], a44[7]);

    // ---- sqrt scales (rcp-based sigmoid) ----
    float sq[8];
#pragma unroll
    for (int j = 0; j < 8; ++j) {
        const float sig = frcp(1.0f + __expf(-a44[8 + j]));
        const float s   = fmaf(SMAX - SMIN, sig, SMIN);
        sq[j] = __builtin_amdgcn_sqrtf(s);
    }

    // ---- R from Givens chain; hw sin/cos in revolutions (R12-validated):
    //      cos(pi*th) = v_cos(th/2), sin(pi*th) = v_sin(th/2) ----
    float R[8][8];
#pragma unroll
    for (int i = 0; i < 8; ++i)
#pragma unroll
        for (int k = 0; k < 8; ++k) R[i][k] = (i == k) ? 1.0f : 0.0f;

    int cc = 0;
#pragma unroll
    for (int i = 0; i < 7; ++i) {
#pragma unroll
        for (int j = i + 1; j < 8; ++j) {
            const float wv  = a44[16 + cc];
            // tanh(wv) = 1 - 2/(e^{2wv}+1); saturates correctly for large |wv|
            const float th  = fmaf(-2.0f, frcp(__expf(2.0f * wv) + 1.0f), 1.0f);
            const float rev = 0.5f * th;
            const float cs  = __builtin_amdgcn_cosf(rev);
            const float ss  = __builtin_amdgcn_sinf(rev);
#pragma unroll
            for (int r = 0; r < 8; ++r) {
                const float ri = R[r][i];
                const float rj = R[r][j];
                R[r][i] = fmaf(ri, cs, rj * ss);
                R[r][j] = fmaf(rj, cs, -(ri * ss));
            }
            ++cc;
        }
    }

    // scale row j by sqrt(s_j):  S = (sqrtD R)^T (sqrtD R)
#pragma unroll
    for (int j = 0; j < 8; ++j)
#pragma unroll
        for (int k = 0; k < 8; ++k) R[j][k] *= sq[j];

    // ---- S rows one at a time -> staging -> coalesced flush per 4 rows ----
    float4* wbuf4 = reinterpret_cast<float4*>(wt);
    float4* S4 = reinterpret_cast<float4*>(out + (size_t)NPIX * 8);
    const size_t pixbase4 = (size_t)W0 * 16;   // float4 units

#pragma unroll
    for (int p = 0; p < 2; ++p) {
#pragma unroll
        for (int r = 0; r < 4; ++r) {
            const int i = 4 * p + r;
            float row[8];
#pragma unroll
            for (int k = 0; k < 8; ++k) {
                float d = 0.0f;
#pragma unroll
                for (int j = 0; j < 8; ++j) d = fmaf(R[j][i], R[j][k], d);
                row[k] = d;
            }
            const int v0 = r * 2, v1 = v0 + 1;
            wbuf4[lane * 8 + (v0 ^ (lane & 7))] =
                make_float4(row[0], row[1], row[2], row[3]);
            wbuf4[lane * 8 + (v1 ^ (lane & 7))] =
                make_float4(row[4], row[5], row[6], row[7]);
        }
        // coalesced flush: 8 iters x 64 lanes x 16B = 8KB contiguous
#pragma unroll
        for (int k = 0; k < 8; ++k) {
            const int t  = k * 64 + lane;
            const int pl = t >> 3;           // local pixel 0..63
            const int v  = t & 7;            // float4 index within half
            S4[pixbase4 + (size_t)pl * 16 + p * 8 + v] =
                wbuf4[pl * 8 + (v ^ (pl & 7))];
        }
    }
}

extern "C" void kernel_launch(void* const* d_in, const int* in_sizes, int n_in,
                              void* d_out, int out_size, void* d_ws, size_t ws_size,
                              hipStream_t stream)
{
    const float* x    = (const float*)d_in[0];
    const float* Wenc = (const float*)d_in[1];
    const float* benc = (const float*)d_in[2];
    float* out        = (float*)d_out;

    dim3 grid(NPIX / 64), block(64);
    sepgpd_fused<<<grid, block, 0, stream>>>(x, Wenc, benc, out);
}

// Round 24
// 27.238 us; speedup vs baseline: 1.6566x; 1.0072x over previous
//
#include <hip/hip_runtime.h>
#include <math.h>

constexpr int IN_C = 31;
constexpr int TOT  = 44;
constexpr int HW   = 256 * 256;
constexpr int NPIX = 4 * HW;
constexpr float SMIN = 0.001f, SMAX = 1000.0f;

typedef __attribute__((ext_vector_type(8))) short bf16x8;
typedef __attribute__((ext_vector_type(4))) float f32x4;

__device__ __forceinline__ float frcp(float v) { return __builtin_amdgcn_rcpf(v); }

__device__ __forceinline__ short f2bf(float f) {
    union { float f; unsigned u; } v; v.f = f;
    unsigned r = v.u + 0x7FFFu + ((v.u >> 16) & 1u);   // RNE
    return (short)(r >> 16);
}
__device__ __forceinline__ float bf2f(short h) {
    union { unsigned u; float f; } v; v.u = ((unsigned)(unsigned short)h) << 16;
    return v.f;
}

// Slim-tail structure (a16 regs + angles-on-demand from LDS + row-at-a-time S)
// under the SAFE (64,4) bound. R23 proved (64,5) miscompiles even the proven
// R20 body, so the bound is reverted; slim tail gets its first clean test.
// If liveness (~85-98) lets the allocator land <=102 VGPR naturally, we get
// the 5-waves/SIMD tier without forcing.
__global__ __launch_bounds__(64, 4) void sepgpd_fused(
    const float* __restrict__ x,
    const float* __restrict__ Wenc,
    const float* __restrict__ benc,
    float* __restrict__ out)
{
    __shared__ float wt[64 * 34];   // 8704 B: transpose + S staging

    const int lane = threadIdx.x;                   // 0..63
    const int W0   = blockIdx.x * 64;               // wave's first pixel
    const int b    = W0 >> 16;                      // 64 | 65536: same image
    const int hwb  = W0 & (HW - 1);
    const int lrow = lane & 15;                     // M/N lane index
    const int lgrp = lane >> 4;                     // K group

    const float* xb = x + (size_t)b * IN_C * HW + hwb;

    // ---- B fragments: W^T tiles (48 chans x 32 K), hi/lo bf16 split ----
    bf16x8 bhi[3], blo[3];
#pragma unroll
    for (int n = 0; n < 3; ++n) {
        const int o = n * 16 + lrow;
#pragma unroll
        for (int j = 0; j < 8; ++j) {
            const int k = lgrp * 8 + j;
            const float wv = (o < TOT && k < IN_C) ? Wenc[o * IN_C + k] : 0.0f;
            const short h = f2bf(wv);
            bhi[n][j] = h;
            blo[n][j] = f2bf(wv - bf2f(h));
        }
    }

    // ---- MFMA: 4 M-tiles x 3 N-tiles x 3 products (x loads per tile) ----
    f32x4 acc[4][3];
#pragma unroll
    for (int t = 0; t < 4; ++t)
#pragma unroll
        for (int n = 0; n < 3; ++n) acc[t][n] = (f32x4)0.0f;

#pragma unroll
    for (int t = 0; t < 4; ++t) {
        float xf[8];
#pragma unroll
        for (int j = 0; j < 8; ++j) {
            const int k = lgrp * 8 + j;
            xf[j] = (k < IN_C) ? xb[(size_t)k * HW + t * 16 + lrow] : 0.0f;
        }
        bf16x8 ahi, alo;
#pragma unroll
        for (int j = 0; j < 8; ++j) {
            const short h = f2bf(xf[j]);
            ahi[j] = h;
            alo[j] = f2bf(xf[j] - bf2f(h));
        }
#pragma unroll
        for (int n = 0; n < 3; ++n) {
            acc[t][n] = __builtin_amdgcn_mfma_f32_16x16x32_bf16(ahi, bhi[n], acc[t][n], 0, 0, 0);
            acc[t][n] = __builtin_amdgcn_mfma_f32_16x16x32_bf16(alo, bhi[n], acc[t][n], 0, 0, 0);
            acc[t][n] = __builtin_amdgcn_mfma_f32_16x16x32_bf16(ahi, blo[n], acc[t][n], 0, 0, 0);
        }
    }

    // ---- transpose phase A: chans 0..31 -> [p][c] stride 34 ----
#pragma unroll
    for (int t = 0; t < 4; ++t)
#pragma unroll
        for (int n = 0; n < 2; ++n)
#pragma unroll
            for (int r = 0; r < 4; ++r) {
                const int p = t * 16 + lgrp * 4 + r;      // pixel (C row)
                wt[p * 34 + n * 16 + lrow] = acc[t][n][r];
            }

    // read chans 0..15 (m + scales) as PLAIN float loads (alias-ordered)
    float a16[16];
#pragma unroll
    for (int c = 0; c < 16; ++c) a16[c] = wt[lane * 34 + c];

    asm volatile("" ::: "memory");   // fence: reads above before phase-B writes

    // phase B: chans 32..43 -> cols 0..15 (cols 16..31 keep angle chans 16..31)
#pragma unroll
    for (int t = 0; t < 4; ++t)
#pragma unroll
        for (int r = 0; r < 4; ++r) {
            const int p = t * 16 + lgrp * 4 + r;
            wt[p * 34 + lrow] = acc[t][2][r];
        }

    // ---- m: first 8 channels (+bias), per-pixel contiguous ----
    const int pix = W0 + lane;
    float4* mp = reinterpret_cast<float4*>(out + (size_t)pix * 8);
    mp[0] = make_float4(a16[0] + benc[0], a16[1] + benc[1],
                        a16[2] + benc[2], a16[3] + benc[3]);
    mp[1] = make_float4(a16[4] + benc[4], a16[5] + benc[5],
                        a16[6] + benc[6], a16[7] + benc[7]);

    // ---- sqrt scales (rcp-based sigmoid) ----
    float sq[8];
#pragma unroll
    for (int j = 0; j < 8; ++j) {
        const float sig = frcp(1.0f + __expf(-(a16[8 + j] + benc[8 + j])));
        const float s   = fmaf(SMAX - SMIN, sig, SMIN);
        sq[j] = __builtin_amdgcn_sqrtf(s);
    }

    // ---- R from Givens chain; angles on demand from LDS (plain float);
    //      hw sin/cos in revolutions: cos(pi*th) = v_cos(th/2) ----
    float R[8][8];
#pragma unroll
    for (int i = 0; i < 8; ++i)
#pragma unroll
        for (int k = 0; k < 8; ++k) R[i][k] = (i == k) ? 1.0f : 0.0f;

    int cc = 0;
#pragma unroll
    for (int i = 0; i < 7; ++i) {
#pragma unroll
        for (int j = i + 1; j < 8; ++j) {
            const int  col = (cc < 16) ? (16 + cc) : (cc - 16);
            const float wv = wt[lane * 34 + col] + benc[16 + cc];
            // tanh(wv) = 1 - 2/(e^{2wv}+1); saturates correctly for large |wv|
            const float th  = fmaf(-2.0f, frcp(__expf(2.0f * wv) + 1.0f), 1.0f);
            const float rev = 0.5f * th;
            const float cs  = __builtin_amdgcn_cosf(rev);
            const float ss  = __builtin_amdgcn_sinf(rev);
#pragma unroll
            for (int r = 0; r < 8; ++r) {
                const float ri = R[r][i];
                const float rj = R[r][j];
                R[r][i] = fmaf(ri, cs, rj * ss);
                R[r][j] = fmaf(rj, cs, -(ri * ss));
            }
            ++cc;
        }
    }

    asm volatile("" ::: "memory");   // fence: angle reads done before staging

    // scale row j by sqrt(s_j):  S = (sqrtD R)^T (sqrtD R)
#pragma unroll
    for (int j = 0; j < 8; ++j)
#pragma unroll
        for (int k = 0; k < 8; ++k) R[j][k] *= sq[j];

    // ---- S rows one at a time -> staging -> coalesced flush per 4 rows ----
    float4* wbuf4 = reinterpret_cast<float4*>(wt);
    float4* S4 = reinterpret_cast<float4*>(out + (size_t)NPIX * 8);
    const size_t pixbase4 = (size_t)W0 * 16;   // float4 units

#pragma unroll
    for (int p = 0; p < 2; ++p) {
#pragma unroll
        for (int r = 0; r < 4; ++r) {
            const int i = 4 * p + r;
            float row[8];
#pragma unroll
            for (int k = 0; k < 8; ++k) {
                float d = 0.0f;
#pragma unroll
                for (int j = 0; j < 8; ++j) d = fmaf(R[j][i], R[j][k], d);
                row[k] = d;
            }
            const int v0 = r * 2, v1 = v0 + 1;
            wbuf4[lane * 8 + (v0 ^ (lane & 7))] =
                make_float4(row[0], row[1], row[2], row[3]);
            wbuf4[lane * 8 + (v1 ^ (lane & 7))] =
                make_float4(row[4], row[5], row[6], row[7]);
        }
        // coalesced flush: 8 iters x 64 lanes x 16B = 8KB contiguous
#pragma unroll
        for (int k = 0; k < 8; ++k) {
            const int t  = k * 64 + lane;
            const int pl = t >> 3;           // local pixel 0..63
            const int v  = t & 7;            // float4 index within half
            S4[pixbase4 + (size_t)pl * 16 + p * 8 + v] =
                wbuf4[pl * 8 + (v ^ (pl & 7))];
        }
    }
}

extern "C" void kernel_launch(void* const* d_in, const int* in_sizes, int n_in,
                              void* d_out, int out_size, void* d_ws, size_t ws_size,
                              hipStream_t stream)
{
    const float* x    = (const float*)d_in[0];
    const float* Wenc = (const float*)d_in[1];
    const float* benc = (const float*)d_in[2];
    float* out        = (float*)d_out;

    dim3 grid(NPIX / 64), block(64);
    sepgpd_fused<<<grid, block, 0, stream>>>(x, Wenc, benc, out);
}